// Round 1
// baseline (818.495 us; speedup 1.0000x reference)
//
#include <hip/hip_runtime.h>
#include <math.h>

#define NB  4
#define NH  8
#define SEQ 512
#define DKC 64
#define TJ  64
#define RSTR 68   // R tile row stride in floats (pad 64+4: keeps float4 alignment, spreads banks)

// One block per (b, i). 256 threads = 8 head-groups of 32 lanes.
// Per j-tile of 64: stage R[i, j0:j0+64, :] in LDS once, use it for BOTH the
// score phase and the value phase (relation streams from HBM exactly once).
// Online softmax per (head) row; P lives in LDS but is written/read by the
// same wave (head-group h = lanes [32h..32h+31] of wave h>>1), so no barrier
// is needed between softmax and the value phase.
__global__ __launch_bounds__(256) void relattn_fwd(
    const float* __restrict__ Q, const float* __restrict__ K,
    const float* __restrict__ V, const float* __restrict__ R,
    const float* __restrict__ M, float* __restrict__ O)
{
    __shared__ __align__(16) float Rs[TJ][RSTR];
    __shared__ __align__(16) float Ps[NH][TJ];

    const int bid = blockIdx.x;
    const int b   = bid >> 9;          // / SEQ
    const int i   = bid & (SEQ - 1);
    const int t   = threadIdx.x;
    const int h   = t >> 5;            // head for this 32-lane group
    const int g   = t & 31;            // lane within group
    const int d4v = g & 15;            // value-phase d-chunk (float4 index)
    const int jh  = g >> 4;            // value-phase j-half (0: j 0..31, 1: j 32..63)

    const float scale = 0.125f;        // 1/sqrt(64)

    // Q row for this head into registers (reused every tile, both j's)
    const float* qrow = Q + (size_t)((b*NH + h)*SEQ + i) * DKC;
    float4 qreg[16];
#pragma unroll
    for (int d4 = 0; d4 < 16; ++d4)
        qreg[d4] = reinterpret_cast<const float4*>(qrow)[d4];

    const float* kbase = K + (size_t)(b*NH + h) * SEQ * DKC;
    const float* vbase = V + (size_t)(b*NH + h) * SEQ * DKC;
    const float* rbase = R + (size_t)(b*SEQ + i) * SEQ * DKC;
    const float* mbase = M + (size_t)((b*NH + h)*SEQ + i) * SEQ;

    float m = -INFINITY, l = 0.f;
    float ax = 0.f, ay = 0.f, az = 0.f, aw = 0.f;   // out accum for (h, d4v, jh)

    for (int j0 = 0; j0 < SEQ; j0 += TJ) {
        __syncthreads();   // previous tile's value-phase reads of Rs are done
        // ---- stage R tile: TJ*DKC = 4096 contiguous floats ----
        {
            const float4* g4 = reinterpret_cast<const float4*>(rbase + (size_t)j0 * DKC);
#pragma unroll
            for (int kk = 0; kk < 4; ++kk) {
                int idx4 = t + 256*kk;           // 0..1023 float4s
                float4 val = g4[idx4];
                int jj = idx4 >> 4;              // 16 float4 per row
                int dd = (idx4 & 15) << 2;
                *reinterpret_cast<float4*>(&Rs[jj][dd]) = val;
            }
        }
        __syncthreads();

        // ---- score phase: this thread computes S[h][g] and S[h][g+32] ----
        const int jt0 = g, jt1 = g + 32;
        float s0 = 0.f, s1 = 0.f;
        const float4* ka4 = reinterpret_cast<const float4*>(kbase + (size_t)(j0 + jt0) * DKC);
        const float4* kb4 = reinterpret_cast<const float4*>(kbase + (size_t)(j0 + jt1) * DKC);
#pragma unroll
        for (int d4 = 0; d4 < 16; ++d4) {
            float4 qv = qreg[d4];
            float4 ra = *reinterpret_cast<const float4*>(&Rs[jt0][d4 << 2]);
            float4 rb = *reinterpret_cast<const float4*>(&Rs[jt1][d4 << 2]);
            float4 ka = ka4[d4];
            float4 kb = kb4[d4];
            s0 = fmaf(qv.x, fmaf(scale, ka.x, ra.x),
                 fmaf(qv.y, fmaf(scale, ka.y, ra.y),
                 fmaf(qv.z, fmaf(scale, ka.z, ra.z),
                 fmaf(qv.w, fmaf(scale, ka.w, ra.w), s0))));
            s1 = fmaf(qv.x, fmaf(scale, kb.x, rb.x),
                 fmaf(qv.y, fmaf(scale, kb.y, rb.y),
                 fmaf(qv.z, fmaf(scale, kb.z, rb.z),
                 fmaf(qv.w, fmaf(scale, kb.w, rb.w), s1))));
        }
        s0 += mbase[j0 + jt0];
        s1 += mbase[j0 + jt1];

        // ---- online softmax over the 32-lane head-group (64 j's this tile) ----
        float tm = fmaxf(s0, s1);
#pragma unroll
        for (int off = 1; off < 32; off <<= 1) tm = fmaxf(tm, __shfl_xor(tm, off));
        float mn  = fmaxf(m, tm);
        float fac = __expf(m - mn);          // first tile: exp(-inf) = 0
        float p0  = __expf(s0 - mn);
        float p1  = __expf(s1 - mn);
        float ps  = p0 + p1;
#pragma unroll
        for (int off = 1; off < 32; off <<= 1) ps += __shfl_xor(ps, off);
        l = l * fac + ps;
        m = mn;
        Ps[h][jt0] = p0;
        Ps[h][jt1] = p1;
        ax *= fac; ay *= fac; az *= fac; aw *= fac;

        // ---- value phase: out[h][4*d4v..+3] += sum_j P*(V + R) over this thread's j-half ----
        const int jbeg = jh << 5;
#pragma unroll
        for (int jj = 0; jj < 32; jj += 4) {
            int jt = jbeg + jj;
            float4 pv = *reinterpret_cast<const float4*>(&Ps[h][jt]);
#pragma unroll
            for (int u = 0; u < 4; ++u) {
                float p = (u == 0) ? pv.x : (u == 1) ? pv.y : (u == 2) ? pv.z : pv.w;
                float4 vv = *reinterpret_cast<const float4*>(
                                vbase + (size_t)(j0 + jt + u) * DKC + (d4v << 2));
                float4 rr = *reinterpret_cast<const float4*>(&Rs[jt + u][d4v << 2]);
                ax = fmaf(p, vv.x + rr.x, ax);
                ay = fmaf(p, vv.y + rr.y, ay);
                az = fmaf(p, vv.z + rr.z, az);
                aw = fmaf(p, vv.w + rr.w, aw);
            }
        }
    }

    // combine the two j-halves (lane g <-> g^16 hold partials of same (h, d4v))
    ax += __shfl_xor(ax, 16);
    ay += __shfl_xor(ay, 16);
    az += __shfl_xor(az, 16);
    aw += __shfl_xor(aw, 16);
    const float inv = 1.0f / l;   // l is the full-row sum (group-reduced every tile)
    if (jh == 0) {
        float4 o = make_float4(ax * inv, ay * inv, az * inv, aw * inv);
        *reinterpret_cast<float4*>(O + (size_t)((b*NH + h)*SEQ + i) * DKC + (d4v << 2)) = o;
    }
}

extern "C" void kernel_launch(void* const* d_in, const int* in_sizes, int n_in,
                              void* d_out, int out_size, void* d_ws, size_t ws_size,
                              hipStream_t stream) {
    const float* Q = (const float*)d_in[0];
    const float* K = (const float*)d_in[1];
    const float* V = (const float*)d_in[2];
    const float* R = (const float*)d_in[3];
    const float* M = (const float*)d_in[4];
    float* O = (float*)d_out;
    // head_num (d_in[5]) is fixed at 8 for this problem shape.
    relattn_fwd<<<dim3(NB * SEQ), dim3(256), 0, stream>>>(Q, K, V, R, M, O);
}

// Round 2
// 681.760 us; speedup vs baseline: 1.2006x; 1.2006x over previous
//
#include <hip/hip_runtime.h>
#include <math.h>

#define NB  4
#define NH  8
#define SEQ 512
#define DKC 64
#define TJ  64
#define RSTR 68   // padded row stride (floats); 68*4=272 B keeps 16B alignment, 2-way banks max

// One block per (b, i). 256 threads = 8 head-groups of 32 lanes.
// Per j-tile of 64: R tile double-buffered in LDS (reg-staged prefetch of tile
// t+1 issued before tile t's compute -> HBM latency hidden; 1 barrier/tile).
// Score phase: lane (jq,dq) computes d-slice dq*16..+15 of rows p*8+jq ->
// coalesced K reads; full score via 2 shfl_xor. Online softmax per head-group.
// Value phase: lane (d4v,jh) accumulates out[4*d4v..+3] over its j-half.
__global__ __launch_bounds__(256) void relattn_fwd(
    const float* __restrict__ Q, const float* __restrict__ K,
    const float* __restrict__ V, const float* __restrict__ R,
    const float* __restrict__ M, float* __restrict__ O)
{
    __shared__ __align__(16) float Rs[2][TJ][RSTR];
    __shared__ __align__(16) float Ps[NH][TJ];

    const int bid = blockIdx.x;
    const int b   = bid >> 9;          // / SEQ
    const int i   = bid & (SEQ - 1);
    const int t   = threadIdx.x;
    const int h   = t >> 5;            // head for this 32-lane group
    const int g   = t & 31;            // lane within group
    const int dq  = g & 3;             // score-phase d-slice (16 floats each)
    const int jq  = g >> 2;            // score-phase row-within-octet
    const int d4v = g & 15;            // value-phase d-chunk (float4 index)
    const int jh  = g >> 4;            // value-phase j-half

    const float scale = 0.125f;        // 1/sqrt(64)

    // Q d-slice for the score phase: only 16 floats per lane
    const float* qrow = Q + (size_t)((b*NH + h)*SEQ + i) * DKC;
    float4 qreg[4];
#pragma unroll
    for (int u = 0; u < 4; ++u)
        qreg[u] = reinterpret_cast<const float4*>(qrow)[dq*4 + u];

    const float* kbase = K + (size_t)(b*NH + h) * SEQ * DKC;
    const float* vbase = V + (size_t)(b*NH + h) * SEQ * DKC;
    const float* rbase = R + (size_t)(b*SEQ + i) * SEQ * DKC;
    const float* mbase = M + (size_t)((b*NH + h)*SEQ + i) * SEQ;
    const float4* rg4  = reinterpret_cast<const float4*>(rbase);

    // prologue: stage tile 0 into registers
    float4 rstage[4];
#pragma unroll
    for (int kk = 0; kk < 4; ++kk) rstage[kk] = rg4[t + 256*kk];

    float m = -INFINITY, l = 0.f;
    float ax = 0.f, ay = 0.f, az = 0.f, aw = 0.f;

    for (int t8 = 0; t8 < 8; ++t8) {
        const int buf = t8 & 1;
        const int j0  = t8 * TJ;

        // ---- write staged tile to LDS ----
#pragma unroll
        for (int kk = 0; kk < 4; ++kk) {
            int idx4 = t + 256*kk;
            *reinterpret_cast<float4*>(&Rs[buf][idx4 >> 4][(idx4 & 15) << 2]) = rstage[kk];
        }
        __syncthreads();

        // ---- prefetch next R tile into registers (drains at next ds_write) ----
        if (t8 < 7) {
            const float4* gnext = rg4 + (size_t)(t8 + 1) * (TJ * DKC / 4);
#pragma unroll
            for (int kk = 0; kk < 4; ++kk) rstage[kk] = gnext[t + 256*kk];
        }

        // ---- score phase: rows p*8+jq, d-slice dq ----
        float sreg[8];
#pragma unroll
        for (int p = 0; p < 8; ++p) {
            const int j = p*8 + jq;
            const float4* k4 = reinterpret_cast<const float4*>(
                                   kbase + (size_t)(j0 + j) * DKC) + dq*4;
            float acc = 0.f;
#pragma unroll
            for (int u = 0; u < 4; ++u) {
                float4 kv = k4[u];
                float4 rv = *reinterpret_cast<const float4*>(&Rs[buf][j][dq*16 + u*4]);
                float4 qv = qreg[u];
                acc = fmaf(qv.x, fmaf(scale, kv.x, rv.x), acc);
                acc = fmaf(qv.y, fmaf(scale, kv.y, rv.y), acc);
                acc = fmaf(qv.z, fmaf(scale, kv.z, rv.z), acc);
                acc = fmaf(qv.w, fmaf(scale, kv.w, rv.w), acc);
            }
            acc += __shfl_xor(acc, 1);   // fold dq quads
            acc += __shfl_xor(acc, 2);
            sreg[p] = acc + mbase[j0 + j];
        }

        // ---- online softmax over the 64 j's of this tile ----
        float tm = sreg[0];
#pragma unroll
        for (int p = 1; p < 8; ++p) tm = fmaxf(tm, sreg[p]);
        tm = fmaxf(tm, __shfl_xor(tm, 4));
        tm = fmaxf(tm, __shfl_xor(tm, 8));
        tm = fmaxf(tm, __shfl_xor(tm, 16));
        const float mn  = fmaxf(m, tm);
        const float fac = __expf(m - mn);
        float ps = 0.f;
#pragma unroll
        for (int p = 0; p < 8; ++p) {
            float pv = __expf(sreg[p] - mn);
            sreg[p] = pv;
            ps += pv;
        }
        ps += __shfl_xor(ps, 4);
        ps += __shfl_xor(ps, 8);
        ps += __shfl_xor(ps, 16);
        l = l * fac + ps;
        m = mn;
        if (dq == 0) {
#pragma unroll
            for (int p = 0; p < 8; ++p) Ps[h][p*8 + jq] = sreg[p];
        }
        ax *= fac; ay *= fac; az *= fac; aw *= fac;

        // ---- value phase: out[h][4*d4v..+3] += sum_j P*(V + R), this j-half ----
        const int jbeg = jh << 5;
#pragma unroll
        for (int jj = 0; jj < 32; jj += 4) {
            const int jt = jbeg + jj;
            float4 pv = *reinterpret_cast<const float4*>(&Ps[h][jt]);
#pragma unroll
            for (int u = 0; u < 4; ++u) {
                float p = (u == 0) ? pv.x : (u == 1) ? pv.y : (u == 2) ? pv.z : pv.w;
                float4 vv = *reinterpret_cast<const float4*>(
                                vbase + (size_t)(j0 + jt + u) * DKC + (d4v << 2));
                float4 rr = *reinterpret_cast<const float4*>(&Rs[buf][jt + u][d4v << 2]);
                ax = fmaf(p, vv.x + rr.x, ax);
                ay = fmaf(p, vv.y + rr.y, ay);
                az = fmaf(p, vv.z + rr.z, az);
                aw = fmaf(p, vv.w + rr.w, aw);
            }
        }
    }

    // combine j-halves (lane g <-> g^16 hold partials of same (h, d4v))
    ax += __shfl_xor(ax, 16);
    ay += __shfl_xor(ay, 16);
    az += __shfl_xor(az, 16);
    aw += __shfl_xor(aw, 16);
    const float inv = 1.0f / l;
    if (jh == 0) {
        float4 o = make_float4(ax * inv, ay * inv, az * inv, aw * inv);
        *reinterpret_cast<float4*>(O + (size_t)((b*NH + h)*SEQ + i) * DKC + (d4v << 2)) = o;
    }
}

extern "C" void kernel_launch(void* const* d_in, const int* in_sizes, int n_in,
                              void* d_out, int out_size, void* d_ws, size_t ws_size,
                              hipStream_t stream) {
    const float* Q = (const float*)d_in[0];
    const float* K = (const float*)d_in[1];
    const float* V = (const float*)d_in[2];
    const float* R = (const float*)d_in[3];
    const float* M = (const float*)d_in[4];
    float* O = (float*)d_out;
    relattn_fwd<<<dim3(NB * SEQ), dim3(256), 0, stream>>>(Q, K, V, R, M, O);
}